// Round 1
// baseline (3593.987 us; speedup 1.0000x reference)
//
#include <hip/hip_runtime.h>
#include <hip/hip_bf16.h>

// Sizes (fixed by the problem)
#define B_   256
#define E_   256
#define H_   256
#define T_   512
#define OUT_ 702
#define G4H  1024   // 4*H

typedef _Float16 half8 __attribute__((ext_vector_type(8)));
typedef float    floatx4 __attribute__((ext_vector_type(4)));
typedef unsigned long long ull;

// Workspace layout (bytes). Total ~69.6 MB.
// hbuf: 4 slots x 16 groups x 16 rows x 64 words x 8B = 512 KB.
//   Word = ~(4 packed fp16). 0 == "not yet written" (impossible as data:
//   would require 4 NaN halves). Slot t&3; producer re-zeroes its own slice
//   of slot (t-2)&3 before publishing t (vmcnt-ordered) -> no flags needed.
#define OFF_DTF    0                          // 1 int dtype flag
#define OFF_HBUF   4096                       // 524288 bytes
#define OFF_BASE   (4096 + 524288)            // 256*1024 fp32 = 1 MB
#define OFF_WC16   (OFF_BASE + 1048576)       // 1024*256 fp16 (W_ih + W_hh)
#define OFF_WREC16 (OFF_WC16 + 524288)        // 704*256 fp16 (padded)
#define OFF_HS16   (OFF_WREC16 + 360448)      // 256*512*256 fp16 = 64 MB

__device__ __forceinline__ float ldin(const void* p, long i, int bf) {
  return bf ? __bfloat162float(((const __hip_bfloat16*)p)[i]) : ((const float*)p)[i];
}
__device__ __forceinline__ void stout(void* p, long i, float v, int bf) {
  if (bf) ((__hip_bfloat16*)p)[i] = __float2bfloat16(v);
  else    ((float*)p)[i] = v;
}
__device__ __forceinline__ float sigf(float x)  { return 1.0f / (1.0f + __expf(-x)); }
__device__ __forceinline__ float tanh_(float x) { float e = __expf(2.0f * x); return 1.0f - 2.0f / (e + 1.0f); }

// ---------------------------------------------------------------------------
// K0: runtime input-dtype detection (unchanged).
__global__ void k_detect(const unsigned int* emb, int* dtf) {
  int tid = threadIdx.x;
  int cnt = 0;
  for (int i = tid; i < 256; i += 64) {
    unsigned int u = emb[i];
    unsigned int e = (u >> 7) & 0xFF;
    cnt += (e >= 100 && e <= 129) ? 1 : 0;
  }
  for (int off = 32; off > 0; off >>= 1) cnt += __shfl_down(cnt, off);
  if (tid == 0) *dtf = (cnt >= 128) ? 1 : 0;
}

// K1: W_comb = W_ih + W_hh -> fp16  [1024][256]
__global__ void k_prep_wc(const void* wih, const void* whh, _Float16* wc, const int* dtf) {
  int bf = *dtf;
  long i = (long)blockIdx.x * 256 + threadIdx.x;
  wc[i] = (_Float16)(ldin(wih, i, bf) + ldin(whh, i, bf));
}

// K1b: W_rec -> fp16, padded to [704][256] with zeros
__global__ void k_prep_wrec(const void* wrec, _Float16* wr, const int* dtf) {
  int bf = *dtf;
  long i = (long)blockIdx.x * 256 + threadIdx.x;   // < 704*256
  wr[i] = (i < (long)OUT_ * H_) ? (_Float16)ldin(wrec, i, bf) : (_Float16)0.0f;
}

// K2: base[b][n] = x0[b]·W_ih[n] + b_ih[n] + b_hh[n]   (fp32, exact)
__global__ void k_prep_base(const void* emb, const void* wih, const void* bih,
                            const void* bhh, float* base, const int* dtf) {
  int bf = *dtf;
  int b = blockIdx.x >> 2;
  int n = (blockIdx.x & 3) * 256 + threadIdx.x;
  __shared__ float x0s[256];
  x0s[threadIdx.x] = ldin(emb, (long)b * E_ + threadIdx.x, bf);
  __syncthreads();
  float acc = ldin(bih, n, bf) + ldin(bhh, n, bf);
  const long wrow = (long)n * E_;
  for (int k = 0; k < E_; ++k) acc += x0s[k] * ldin(wih, wrow + k, bf);
  base[(long)b * G4H + n] = acc;
}

// ---------------------------------------------------------------------------
// K3: persistent LSTM recurrence — flag-free one-round-trip exchange.
// Grid: 256 blocks x 256 threads. group g = blockIdx>>4 owns batch rows
// [16g,16g+16); member m = blockIdx&15 owns hidden cols [16m,16m+16).
// Per step:
//   MFMA (A-frags live in registers from last gather) -> gates_lds (parity
//   double-buffered, ONE syncthreads) -> pointwise -> shuffle-pack own
//   16x16 h slice -> [reset slot (t-2)&3] vmcnt(0) [publish ~packed to
//   slot t&3] -> poll peers' words directly into next step's A-fragment
//   registers (word != 0 <=> present). No flags, no h_lds, no s_sleep.
__global__ void __launch_bounds__(256) k_lstm(char* ws, void* dout, const int* dtf) {
  const int bf  = *dtf;
  const int tid = threadIdx.x;
  const int g   = blockIdx.x >> 4;
  const int mem = blockIdx.x & 15;
  const int wid = tid >> 6;
  const int lane = tid & 63;
  const int q = lane >> 4;
  const int r = lane & 15;

  _Float16* wc   = (_Float16*)(ws + OFF_WC16);
  float*    base = (float*)(ws + OFF_BASE);
  ull*      hbuf = (ull*)(ws + OFF_HBUF);
  _Float16* hs16 = (_Float16*)(ws + OFF_HS16);

  // B-fragments: lane holds Wc[n = wid*256 + mem*16 + r][kb*32 + q*8 .. +8]
  half8 wfrag[8];
  {
    const long wrow = (long)(wid * 256 + mem * 16 + r) * H_;
#pragma unroll
    for (int kb = 0; kb < 8; ++kb)
      wfrag[kb] = *(const half8*)(wc + wrow + kb * 32 + q * 8);
  }

  const int m  = tid >> 4;   // local batch row for pointwise phase
  const int jl = tid & 15;   // local hidden col
  float basev[4];
  {
    const long brow = (long)(g * 16 + m) * G4H + mem * 16 + jl;
#pragma unroll
    for (int ty = 0; ty < 4; ++ty) basev[ty] = base[brow + ty * 256];
  }

  __shared__ float gates_lds[2][16][68];   // parity-buffered [par][m][gate*16+jl]

  // hbuf word indices (within a slot of 16384 words):
  //  gather: lane (q,r) needs row r, chunks kb*8 + q*2 + {0,1}  (col = chunk*4)
  //  publish: lanes with jl%4==0 store chunk mem*4 + jl/4 of row m
  const int gword = (g * 16 + r) * 64 + q * 2;
  const int pword = (g * 16 + m) * 64 + mem * 4 + (jl >> 2);
  const bool packer = ((tid & 3) == 0);

  // A-fragment words (decoded; 0 == h_prev = 0 for t=0)
  ull av[16];
#pragma unroll
  for (int w = 0; w < 16; ++w) av[w] = 0;

  float c = 0.0f;
  const long out2off = (long)B_ * T_ * OUT_;
  const long orow_base = ((long)(g * 16 + m) * T_) * H_ + mem * 16 + jl;

  for (int t = 0; t < T_; ++t) {
    // gates(own 64 cols) = h_prev @ Wslice^T, A-fragments straight from av
    floatx4 acc = {0.f, 0.f, 0.f, 0.f};
#pragma unroll
    for (int kb = 0; kb < 8; ++kb) {
      union { ull u[2]; half8 h; } ua;
      ua.u[0] = av[2 * kb];
      ua.u[1] = av[2 * kb + 1];
      acc = __builtin_amdgcn_mfma_f32_16x16x32_f16(ua.h, wfrag[kb], acc, 0, 0, 0);
    }
    const int par = t & 1;
#pragma unroll
    for (int e = 0; e < 4; ++e) gates_lds[par][q * 4 + e][wid * 16 + r] = acc[e];
    __syncthreads();

    float gi = gates_lds[par][m][jl]      + basev[0];
    float gf = gates_lds[par][m][16 + jl] + basev[1];
    float gg = gates_lds[par][m][32 + jl] + basev[2];
    float go = gates_lds[par][m][48 + jl] + basev[3];
    c = sigf(gf) * c + sigf(gi) * tanh_(gg);
    float h = sigf(go) * tanh_(c);

    if (t < T_ - 1) {
      const int slot = t & 3;
      // pack 4 consecutive lanes' fp16 into one word (all lanes shuffle)
      union { _Float16 f; unsigned short u; } cv; cv.f = (_Float16)h;
      unsigned int hu = cv.u;
      const int lb = lane & ~3;
      unsigned int u0 = __shfl(hu, lb);
      unsigned int u1 = __shfl(hu, lb + 1);
      unsigned int u2 = __shfl(hu, lb + 2);
      unsigned int u3 = __shfl(hu, lb + 3);

      // reset own slice in slot (t-2)&3 (reused at t+2) — must commit
      // before our publish of t becomes visible: vmcnt(0) orders it.
      if (packer && t >= 2)
        __hip_atomic_store(&hbuf[((long)((t - 2) & 3) << 14) + pword], 0ULL,
                           __ATOMIC_RELAXED, __HIP_MEMORY_SCOPE_AGENT);
      asm volatile("s_waitcnt vmcnt(0)" ::: "memory");
      if (packer) {
        ull w = (ull)(u0 & 0xFFFFu)
              | ((ull)(u1 & 0xFFFFu) << 16)
              | ((ull)(u2 & 0xFFFFu) << 32)
              | ((ull)(u3 & 0xFFFFu) << 48);
        __hip_atomic_store(&hbuf[((long)slot << 14) + pword], ~w,
                           __ATOMIC_RELAXED, __HIP_MEMORY_SCOPE_AGENT);
      }

      // stream outputs while the publish propagates
      stout(dout, out2off + orow_base + (long)t * H_, h, bf);
      hs16[orow_base + (long)t * H_] = (_Float16)h;

      // gather h_t directly into next step's A-fragment registers.
      const ull* sb = hbuf + ((long)slot << 14);
      unsigned int pend = 0xFFFFu;
      int guard = 0;
      while (pend) {
        const unsigned int snap = pend;
        ull tmp[16];
#pragma unroll
        for (int w = 0; w < 16; ++w)
          if (snap & (1u << w))
            tmp[w] = __hip_atomic_load(sb + gword + ((w >> 1) << 3) + (w & 1),
                                       __ATOMIC_RELAXED, __HIP_MEMORY_SCOPE_AGENT);
#pragma unroll
        for (int w = 0; w < 16; ++w)
          if (snap & (1u << w)) {
            if (tmp[w]) { av[w] = ~tmp[w]; pend &= ~(1u << w); }
          }
        if (++guard > 200000) break;   // safety: wrong > hung
      }
    } else {
      stout(dout, out2off + orow_base + (long)t * H_, h, bf);
      hs16[orow_base + (long)t * H_] = (_Float16)h;
    }
  }
}

// ---------------------------------------------------------------------------
// K4: projection  out1[M=131072][702] = hs16[M][256] @ Wrec16^T + b_rec
// (unchanged from previous round)
__global__ void __launch_bounds__(256) k_proj(const char* ws, const void* brec,
                                              void* dout, const int* dtf) {
  const int bf  = *dtf;
  const int tid = threadIdx.x;
  const int wid = tid >> 6, lane = tid & 63, q = lane >> 4, r = lane & 15;
  const int mb = blockIdx.x & 2047, nb = blockIdx.x >> 11;
  const long mbase = (long)mb * 64;
  const int  nbase = nb * 192;
  const _Float16* hs16 = (const _Float16*)(ws + OFF_HS16);
  const _Float16* wr16 = (const _Float16*)(ws + OFF_WREC16);

  __shared__ _Float16 a_lds[64][264];
#pragma unroll
  for (int i = 0; i < 8; ++i) {
    int u = tid + i * 256;              // 2048 units of 8 halves
    int row = u >> 5, c8 = (u & 31) * 8;
    half8 v = *(const half8*)(hs16 + (mbase + row) * H_ + c8);
    *(half8*)(&a_lds[row][c8]) = v;
  }
  __syncthreads();

  half8 bfrag[3][8];
  float bias[3];
#pragma unroll
  for (int j = 0; j < 3; ++j) {
    int ncol = nbase + (wid * 3 + j) * 16 + r;
    bias[j] = 0.0f;
    if (ncol < 704) {
      const long wrow = (long)ncol * H_;
#pragma unroll
      for (int kb = 0; kb < 8; ++kb)
        bfrag[j][kb] = *(const half8*)(wr16 + wrow + kb * 32 + q * 8);
    } else {
      half8 z = {0, 0, 0, 0, 0, 0, 0, 0};
#pragma unroll
      for (int kb = 0; kb < 8; ++kb) bfrag[j][kb] = z;
    }
    if (ncol < OUT_) bias[j] = ldin(brec, ncol, bf);
  }

  floatx4 acc[3][4];
#pragma unroll
  for (int j = 0; j < 3; ++j)
#pragma unroll
    for (int ms = 0; ms < 4; ++ms) acc[j][ms] = (floatx4){0.f, 0.f, 0.f, 0.f};

#pragma unroll
  for (int ms = 0; ms < 4; ++ms) {
#pragma unroll
    for (int kb = 0; kb < 8; ++kb) {
      half8 a = *(const half8*)(&a_lds[ms * 16 + r][kb * 32 + q * 8]);
#pragma unroll
      for (int j = 0; j < 3; ++j)
        acc[j][ms] = __builtin_amdgcn_mfma_f32_16x16x32_f16(a, bfrag[j][kb], acc[j][ms], 0, 0, 0);
    }
  }

#pragma unroll
  for (int j = 0; j < 3; ++j) {
    int ncol = nbase + (wid * 3 + j) * 16 + r;
    if (ncol >= OUT_) continue;
#pragma unroll
    for (int ms = 0; ms < 4; ++ms) {
#pragma unroll
      for (int e = 0; e < 4; ++e) {
        long mrow = mbase + ms * 16 + q * 4 + e;
        stout(dout, mrow * (long)OUT_ + ncol, acc[j][ms][e] + bias[j], bf);
      }
    }
  }
}

// ---------------------------------------------------------------------------
extern "C" void kernel_launch(void* const* d_in, const int* in_sizes, int n_in,
                              void* d_out, int out_size, void* d_ws, size_t ws_size,
                              hipStream_t stream) {
  const void* embed = d_in[0];
  const void* W_ih  = d_in[1];
  const void* W_hh  = d_in[2];
  const void* b_ih  = d_in[3];
  const void* b_hh  = d_in[4];
  const void* W_rec = d_in[5];
  const void* b_rec = d_in[6];
  char* ws = (char*)d_ws;
  const int* dtf = (const int*)(ws + OFF_DTF);

  // zero dtf + all 4 hbuf slots every launch — replay-safe (0 == "not yet")
  hipMemsetAsync(ws, 0, OFF_BASE, stream);
  k_detect<<<1, 64, 0, stream>>>((const unsigned int*)embed, (int*)(ws + OFF_DTF));
  k_prep_wc<<<1024, 256, 0, stream>>>(W_ih, W_hh, (_Float16*)(ws + OFF_WC16), dtf);
  k_prep_wrec<<<704, 256, 0, stream>>>(W_rec, (_Float16*)(ws + OFF_WREC16), dtf);
  k_prep_base<<<1024, 256, 0, stream>>>(embed, W_ih, b_ih, b_hh, (float*)(ws + OFF_BASE), dtf);
  k_lstm<<<256, 256, 0, stream>>>(ws, d_out, dtf);
  k_proj<<<8192, 256, 0, stream>>>(ws, b_rec, d_out, dtf);
}

// Round 3
// 1682.377 us; speedup vs baseline: 2.1363x; 2.1363x over previous
//
#include <hip/hip_runtime.h>
#include <hip/hip_bf16.h>

// Sizes (fixed by the problem)
#define B_   256
#define E_   256
#define H_   256
#define T_   512
#define OUT_ 702
#define G4H  1024   // 4*H

typedef _Float16 half8 __attribute__((ext_vector_type(8)));
typedef float    floatx4 __attribute__((ext_vector_type(4)));
typedef unsigned long long ull;

// Workspace layout (bytes). Total ~69.6 MB.
// hbuf: 4 slots x 16 groups x 16 rows x 64 words x 8B = 512 KB.
//   Word = ~(4 packed fp16). 0 == "not yet written" (impossible as data:
//   would require 4 NaN halves). Slot t&3; producer re-zeroes its own word
//   of slot (t-2)&3 alongside publishing t; the step-t gather's trailing
//   vmcnt(0) commits both before publish(t+1) is issued -> a consumer that
//   observed publish(t+1) can never see pre-reset slot contents. No flags.
#define OFF_DTF    0                          // 1 int dtype flag
#define OFF_HBUF   4096                       // 524288 bytes
#define OFF_BASE   (4096 + 524288)            // 256*1024 fp32 = 1 MB
#define OFF_WC16   (OFF_BASE + 1048576)       // 1024*256 fp16 (W_ih + W_hh)
#define OFF_WREC16 (OFF_WC16 + 524288)        // 704*256 fp16 (padded)
#define OFF_HS16   (OFF_WREC16 + 360448)      // 256*512*256 fp16 = 64 MB

__device__ __forceinline__ float ldin(const void* p, long i, int bf) {
  return bf ? __bfloat162float(((const __hip_bfloat16*)p)[i]) : ((const float*)p)[i];
}
__device__ __forceinline__ void stout(void* p, long i, float v, int bf) {
  if (bf) ((__hip_bfloat16*)p)[i] = __float2bfloat16(v);
  else    ((float*)p)[i] = v;
}
__device__ __forceinline__ float sigf(float x)  { return 1.0f / (1.0f + __expf(-x)); }
__device__ __forceinline__ float tanh_(float x) { float e = __expf(2.0f * x); return 1.0f - 2.0f / (e + 1.0f); }

// ---------------------------------------------------------------------------
// K0: runtime input-dtype detection (unchanged).
__global__ void k_detect(const unsigned int* emb, int* dtf) {
  int tid = threadIdx.x;
  int cnt = 0;
  for (int i = tid; i < 256; i += 64) {
    unsigned int u = emb[i];
    unsigned int e = (u >> 7) & 0xFF;
    cnt += (e >= 100 && e <= 129) ? 1 : 0;
  }
  for (int off = 32; off > 0; off >>= 1) cnt += __shfl_down(cnt, off);
  if (tid == 0) *dtf = (cnt >= 128) ? 1 : 0;
}

// K1: W_comb = W_ih + W_hh -> fp16  [1024][256]
__global__ void k_prep_wc(const void* wih, const void* whh, _Float16* wc, const int* dtf) {
  int bf = *dtf;
  long i = (long)blockIdx.x * 256 + threadIdx.x;
  wc[i] = (_Float16)(ldin(wih, i, bf) + ldin(whh, i, bf));
}

// K1b: W_rec -> fp16, padded to [704][256] with zeros
__global__ void k_prep_wrec(const void* wrec, _Float16* wr, const int* dtf) {
  int bf = *dtf;
  long i = (long)blockIdx.x * 256 + threadIdx.x;   // < 704*256
  wr[i] = (i < (long)OUT_ * H_) ? (_Float16)ldin(wrec, i, bf) : (_Float16)0.0f;
}

// K2: base[b][n] = x0[b]·W_ih[n] + b_ih[n] + b_hh[n]   (fp32, exact)
__global__ void k_prep_base(const void* emb, const void* wih, const void* bih,
                            const void* bhh, float* base, const int* dtf) {
  int bf = *dtf;
  int b = blockIdx.x >> 2;
  int n = (blockIdx.x & 3) * 256 + threadIdx.x;
  __shared__ float x0s[256];
  x0s[threadIdx.x] = ldin(emb, (long)b * E_ + threadIdx.x, bf);
  __syncthreads();
  float acc = ldin(bih, n, bf) + ldin(bhh, n, bf);
  const long wrow = (long)n * E_;
  for (int k = 0; k < E_; ++k) acc += x0s[k] * ldin(wih, wrow + k, bf);
  base[(long)b * G4H + n] = acc;
}

// ---------------------------------------------------------------------------
// K3: persistent LSTM recurrence — single-round-trip exchange with
// UNIQUE-word polling (R1 post-mortem: 256 threads x 16 masked polls
// quadrupled readers/word and flooded vmem issue; here each of the 1024
// hbuf words of a group is polled by exactly ONE thread per member block,
// same contention profile as R0's flags, but the successful poll IS the
// data fetch — the flag round trip is gone).
// Hardened vs R2 submission: poll guard 2M -> 500K rounds (a stuck
// protocol now produces a fast failing answer, not a container timeout)
// and s_sleep(1) backoff after 256 failed rounds (bounds LLC hammering;
// free in the common case where data lands within ~1 round trip).
// Grid: 256 blocks x 256 threads. group g = blockIdx>>4 owns batch rows
// [16g,16g+16); member m = blockIdx&15 owns hidden cols [16m,16m+16).
// Per step (2 syncthreads, no parity buffers):
//   MFMA (A from h_lds) -> gates_lds -> sync -> pointwise -> shuffle-pack
//   -> publish ~packed + reset slot (t-2)&3 (packers, fire) -> stream
//   outputs -> poll own 4 unique words until nonzero -> h_lds write
//   (lane-consecutive: 2-way bank alias = free) -> sync.
__global__ void __launch_bounds__(256) k_lstm(char* ws, void* dout, const int* dtf) {
  const int bf  = *dtf;
  const int tid = threadIdx.x;
  const int g   = blockIdx.x >> 4;
  const int mem = blockIdx.x & 15;
  const int wid = tid >> 6;
  const int lane = tid & 63;
  const int q = lane >> 4;
  const int r = lane & 15;

  _Float16* wc   = (_Float16*)(ws + OFF_WC16);
  float*    base = (float*)(ws + OFF_BASE);
  ull*      hbuf = (ull*)(ws + OFF_HBUF);
  _Float16* hs16 = (_Float16*)(ws + OFF_HS16);

  // B-fragments: lane holds Wc[n = wid*256 + mem*16 + r][kb*32 + q*8 .. +8]
  half8 wfrag[8];
  {
    const long wrow = (long)(wid * 256 + mem * 16 + r) * H_;
#pragma unroll
    for (int kb = 0; kb < 8; ++kb)
      wfrag[kb] = *(const half8*)(wc + wrow + kb * 32 + q * 8);
  }

  const int m  = tid >> 4;   // local batch row for pointwise phase
  const int jl = tid & 15;   // local hidden col
  float basev[4];
  {
    const long brow = (long)(g * 16 + m) * G4H + mem * 16 + jl;
#pragma unroll
    for (int ty = 0; ty < 4; ++ty) basev[ty] = base[brow + ty * 256];
  }

  __shared__ _Float16 h_lds[16][264];   // stride 528B: MFMA ds_read_b128 2-way (free)
  __shared__ float gates_lds[16][68];   // [m][gate*16+jl]
  for (int i = tid; i < 16 * 264; i += 256) (&h_lds[0][0])[i] = (_Float16)0.0f;
  float c = 0.0f;
  __syncthreads();

  const long out2off = (long)B_ * T_ * OUT_;
  const long orow_base = ((long)(g * 16 + m) * T_) * H_ + mem * 16 + jl;

  // publish: packer (jl%4==0) stores word (row m, word-col mem*4 + jl/4)
  const bool packer = ((jl & 3) == 0);
  const int pword = (g * 16 + m) * 64 + mem * 4 + (jl >> 2);
  // gather: lane l of wave w polls rows 4w+i (i=0..3), word-col l — unique
  const int grow = g * 16 + wid * 4;

  for (int t = 0; t < T_; ++t) {
    // gates(own 64 cols) = h_prev @ Wslice^T  (t=0: h_lds = 0)
    floatx4 acc = {0.f, 0.f, 0.f, 0.f};
#pragma unroll
    for (int kb = 0; kb < 8; ++kb) {
      half8 a = *(const half8*)(&h_lds[r][kb * 32 + q * 8]);
      acc = __builtin_amdgcn_mfma_f32_16x16x32_f16(a, wfrag[kb], acc, 0, 0, 0);
    }
#pragma unroll
    for (int e = 0; e < 4; ++e) gates_lds[q * 4 + e][wid * 16 + r] = acc[e];
    __syncthreads();                               // sync #1

    float gi = gates_lds[m][jl]      + basev[0];
    float gf = gates_lds[m][16 + jl] + basev[1];
    float gg = gates_lds[m][32 + jl] + basev[2];
    float go = gates_lds[m][48 + jl] + basev[3];
    c = sigf(gf) * c + sigf(gi) * tanh_(gg);
    float h = sigf(go) * tanh_(c);

    if (t < T_ - 1) {
      const int slot = t & 3;
      // pack 4 consecutive lanes' fp16 into one word (all lanes shuffle)
      union { _Float16 f; unsigned short u; } cv; cv.f = (_Float16)h;
      unsigned int hu = cv.u;
      const int lb = lane & ~3;
      unsigned int u0 = __shfl(hu, lb);
      unsigned int u1 = __shfl(hu, lb + 1);
      unsigned int u2 = __shfl(hu, lb + 2);
      unsigned int u3 = __shfl(hu, lb + 3);
      if (packer) {
        if (t >= 2)
          __hip_atomic_store(&hbuf[((long)((t - 2) & 3) << 14) + pword], 0ULL,
                             __ATOMIC_RELAXED, __HIP_MEMORY_SCOPE_AGENT);
        ull w = (ull)(u0 & 0xFFFFu)
              | ((ull)(u1 & 0xFFFFu) << 16)
              | ((ull)(u2 & 0xFFFFu) << 32)
              | ((ull)(u3 & 0xFFFFu) << 48);
        __hip_atomic_store(&hbuf[((long)slot << 14) + pword], ~w,
                           __ATOMIC_RELAXED, __HIP_MEMORY_SCOPE_AGENT);
      }

      // stream outputs while the publish propagates
      stout(dout, out2off + orow_base + (long)t * H_, h, bf);
      hs16[orow_base + (long)t * H_] = (_Float16)h;

      // poll own 4 unique words; success == data in hand (one round trip)
      const ull* sb = hbuf + ((long)slot << 14);
      ull d[4] = {0, 0, 0, 0};
      unsigned int pend = 0xFu;
      int guard = 0;
      while (pend) {
        const unsigned int snap = pend;
        ull tmp[4];
#pragma unroll
        for (int i = 0; i < 4; ++i)
          if (snap & (1u << i))
            tmp[i] = __hip_atomic_load(&sb[(long)(grow + i) * 64 + lane],
                                       __ATOMIC_RELAXED, __HIP_MEMORY_SCOPE_AGENT);
#pragma unroll
        for (int i = 0; i < 4; ++i)
          if (snap & (1u << i)) {
            if (tmp[i]) { d[i] = ~tmp[i]; pend &= ~(1u << i); }
          }
        ++guard;
        if (guard > 256) __builtin_amdgcn_s_sleep(1);   // backoff: cap LLC hammering
        if (guard > 500000) break;                      // safety: fast-wrong > hung
      }
      // drain: publish + reset committed before anyone's next-step evidence
      asm volatile("s_waitcnt vmcnt(0)" ::: "memory");
#pragma unroll
      for (int i = 0; i < 4; ++i)
        *(ull*)(&h_lds[wid * 4 + i][lane * 4]) = d[i];
      __syncthreads();                             // sync #2
    } else {
      stout(dout, out2off + orow_base + (long)t * H_, h, bf);
      hs16[orow_base + (long)t * H_] = (_Float16)h;
    }
  }
}

// ---------------------------------------------------------------------------
// K4: projection  out1[M=131072][702] = hs16[M][256] @ Wrec16^T + b_rec
// (unchanged — verified good)
__global__ void __launch_bounds__(256) k_proj(const char* ws, const void* brec,
                                              void* dout, const int* dtf) {
  const int bf  = *dtf;
  const int tid = threadIdx.x;
  const int wid = tid >> 6, lane = tid & 63, q = lane >> 4, r = lane & 15;
  const int mb = blockIdx.x & 2047, nb = blockIdx.x >> 11;
  const long mbase = (long)mb * 64;
  const int  nbase = nb * 192;
  const _Float16* hs16 = (const _Float16*)(ws + OFF_HS16);
  const _Float16* wr16 = (const _Float16*)(ws + OFF_WREC16);

  __shared__ _Float16 a_lds[64][264];
#pragma unroll
  for (int i = 0; i < 8; ++i) {
    int u = tid + i * 256;              // 2048 units of 8 halves
    int row = u >> 5, c8 = (u & 31) * 8;
    half8 v = *(const half8*)(hs16 + (mbase + row) * H_ + c8);
    *(half8*)(&a_lds[row][c8]) = v;
  }
  __syncthreads();

  half8 bfrag[3][8];
  float bias[3];
#pragma unroll
  for (int j = 0; j < 3; ++j) {
    int ncol = nbase + (wid * 3 + j) * 16 + r;
    bias[j] = 0.0f;
    if (ncol < 704) {
      const long wrow = (long)ncol * H_;
#pragma unroll
      for (int kb = 0; kb < 8; ++kb)
        bfrag[j][kb] = *(const half8*)(wr16 + wrow + kb * 32 + q * 8);
    } else {
      half8 z = {0, 0, 0, 0, 0, 0, 0, 0};
#pragma unroll
      for (int kb = 0; kb < 8; ++kb) bfrag[j][kb] = z;
    }
    if (ncol < OUT_) bias[j] = ldin(brec, ncol, bf);
  }

  floatx4 acc[3][4];
#pragma unroll
  for (int j = 0; j < 3; ++j)
#pragma unroll
    for (int ms = 0; ms < 4; ++ms) acc[j][ms] = (floatx4){0.f, 0.f, 0.f, 0.f};

#pragma unroll
  for (int ms = 0; ms < 4; ++ms) {
#pragma unroll
    for (int kb = 0; kb < 8; ++kb) {
      half8 a = *(const half8*)(&a_lds[ms * 16 + r][kb * 32 + q * 8]);
#pragma unroll
      for (int j = 0; j < 3; ++j)
        acc[j][ms] = __builtin_amdgcn_mfma_f32_16x16x32_f16(a, bfrag[j][kb], acc[j][ms], 0, 0, 0);
    }
  }

#pragma unroll
  for (int j = 0; j < 3; ++j) {
    int ncol = nbase + (wid * 3 + j) * 16 + r;
    if (ncol >= OUT_) continue;
#pragma unroll
    for (int ms = 0; ms < 4; ++ms) {
#pragma unroll
      for (int e = 0; e < 4; ++e) {
        long mrow = mbase + ms * 16 + q * 4 + e;
        stout(dout, mrow * (long)OUT_ + ncol, acc[j][ms][e] + bias[j], bf);
      }
    }
  }
}

// ---------------------------------------------------------------------------
extern "C" void kernel_launch(void* const* d_in, const int* in_sizes, int n_in,
                              void* d_out, int out_size, void* d_ws, size_t ws_size,
                              hipStream_t stream) {
  const void* embed = d_in[0];
  const void* W_ih  = d_in[1];
  const void* W_hh  = d_in[2];
  const void* b_ih  = d_in[3];
  const void* b_hh  = d_in[4];
  const void* W_rec = d_in[5];
  const void* b_rec = d_in[6];
  char* ws = (char*)d_ws;
  const int* dtf = (const int*)(ws + OFF_DTF);

  // zero dtf + all 4 hbuf slots every launch — replay-safe (0 == "not yet")
  hipMemsetAsync(ws, 0, OFF_BASE, stream);
  k_detect<<<1, 64, 0, stream>>>((const unsigned int*)embed, (int*)(ws + OFF_DTF));
  k_prep_wc<<<1024, 256, 0, stream>>>(W_ih, W_hh, (_Float16*)(ws + OFF_WC16), dtf);
  k_prep_wrec<<<704, 256, 0, stream>>>(W_rec, (_Float16*)(ws + OFF_WREC16), dtf);
  k_prep_base<<<1024, 256, 0, stream>>>(embed, W_ih, b_ih, b_hh, (float*)(ws + OFF_BASE), dtf);
  k_lstm<<<256, 256, 0, stream>>>(ws, d_out, dtf);
  k_proj<<<8192, 256, 0, stream>>>(ws, b_rec, d_out, dtf);
}